// Round 16
// baseline (439.503 us; speedup 1.0000x reference)
//
#include <hip/hip_runtime.h>
#include <hip/hip_bf16.h>

// ---------------------------------------------------------------------------
// GCN forward, round 16.
//   k_mfma<MFRAG>: frozen R13 GEMM (128x128 hidden / 64x128 layer-4).
//   k_agg_h/k_agg_o: R15 structure with ALL gather/epilogue addressing in
//           int32 (Lin spans 41MB < 2^31 bytes) -> compiler emits
//           global_load v_off32 + SGPR base instead of 64-bit v_mad chains.
//   preamble: cnt zero via hipMemsetAsync; dinv fused into k_scan.
// ---------------------------------------------------------------------------

#define THREADS 256

typedef __bf16 bf16_t;
typedef __bf16 bf16x8 __attribute__((ext_vector_type(8)));
typedef __bf16 bf16x4 __attribute__((ext_vector_type(4)));
typedef float  f32x4  __attribute__((ext_vector_type(4)));

typedef const __attribute__((address_space(1))) void* gas_ptr;
typedef __attribute__((address_space(3))) void*       las_ptr;

// ------------------------------ CSR build ----------------------------------

__global__ void k_count(const int* __restrict__ dst, int* __restrict__ cnt, int E, int n) {
    int i = blockIdx.x * blockDim.x + threadIdx.x;
    if (i < E) {
        int d = dst[i];
        if ((unsigned)d < (unsigned)n) atomicAdd(&cnt[d], 1);
    }
}

// exclusive scan of cnt -> row_ptr/cursor, plus dinv = rsqrt(cnt+1) fused
__global__ __launch_bounds__(1024) void k_scan(const int* __restrict__ cnt,
                                               int* __restrict__ row_ptr,
                                               int* __restrict__ cursor,
                                               float* __restrict__ dinv, int n)
{
    __shared__ int sm[1024];
    const int t = threadIdx.x;
    const int chunk = (n + 1023) >> 10;
    const int lo = t * chunk, hi = min(n, lo + chunk);
    int s = 0;
    for (int i = lo; i < hi; ++i) s += cnt[i];
    sm[t] = s;
    __syncthreads();
    for (int off = 1; off < 1024; off <<= 1) {
        int v = (t >= off) ? sm[t - off] : 0;
        __syncthreads();
        sm[t] += v;
        __syncthreads();
    }
    int run = sm[t] - s;
    for (int i = lo; i < hi; ++i) {
        row_ptr[i] = run;
        cursor[i]  = run;
        dinv[i]    = rsqrtf((float)(cnt[i] + 1));
        run += cnt[i];
    }
}

__global__ void k_fill(const int* __restrict__ src, const int* __restrict__ dst,
                       const float* __restrict__ dinv, int* __restrict__ cursor,
                       int2* __restrict__ ew, int E, int n)
{
    int i = blockIdx.x * blockDim.x + threadIdx.x;
    if (i < E) {
        int s = src[i], d = dst[i];
        if ((unsigned)s >= (unsigned)n || (unsigned)d >= (unsigned)n) return;
        int pos = atomicAdd(&cursor[d], 1);
        ew[pos] = make_int2(s, __float_as_int(dinv[s]));
    }
}

// --------------------------- f32 -> hi/lo bf16 -----------------------------

__global__ void k_split(const float* __restrict__ in, bf16_t* __restrict__ hi,
                        bf16_t* __restrict__ lo, int n4)
{
    int i = blockIdx.x * blockDim.x + threadIdx.x;
    const int stride = gridDim.x * blockDim.x;
    for (; i < n4; i += stride) {
        float4 v = ((const float4*)in)[i];
        bf16x4 h, l;
        h[0] = (bf16_t)v.x; l[0] = (bf16_t)(v.x - (float)h[0]);
        h[1] = (bf16_t)v.y; l[1] = (bf16_t)(v.y - (float)h[1]);
        h[2] = (bf16_t)v.z; l[2] = (bf16_t)(v.z - (float)h[2]);
        h[3] = (bf16_t)v.w; l[3] = (bf16_t)(v.w - (float)h[3]);
        ((bf16x4*)hi)[i] = h;
        ((bf16x4*)lo)[i] = l;
    }
}

// fused 4-weight split
__global__ void k_split_w(const float* __restrict__ s0, const float* __restrict__ s1,
                          const float* __restrict__ s2, const float* __restrict__ s3,
                          bf16_t* __restrict__ h0, bf16_t* __restrict__ h1,
                          bf16_t* __restrict__ h2, bf16_t* __restrict__ h3,
                          bf16_t* __restrict__ l0, bf16_t* __restrict__ l1,
                          bf16_t* __restrict__ l2, bf16_t* __restrict__ l3,
                          int a, int b, int c, int d)
{
    int i = blockIdx.x * blockDim.x + threadIdx.x;
    const int stride = gridDim.x * blockDim.x;
    for (; i < d; i += stride) {
        const float* src; bf16_t* hh; bf16_t* ll; int j;
        if (i < a)      { src = s0; hh = h0; ll = l0; j = i; }
        else if (i < b) { src = s1; hh = h1; ll = l1; j = i - a; }
        else if (i < c) { src = s2; hh = h2; ll = l2; j = i - b; }
        else            { src = s3; hh = h3; ll = l3; j = i - c; }
        float4 v = ((const float4*)src)[j];
        bf16x4 h, l;
        h[0] = (bf16_t)v.x; l[0] = (bf16_t)(v.x - (float)h[0]);
        h[1] = (bf16_t)v.y; l[1] = (bf16_t)(v.y - (float)h[1]);
        h[2] = (bf16_t)v.z; l[2] = (bf16_t)(v.z - (float)h[2]);
        h[3] = (bf16_t)v.w; l[3] = (bf16_t)(v.w - (float)h[3]);
        ((bf16x4*)hh)[j] = h;
        ((bf16x4*)ll)[j] = l;
    }
}

// ------------------------ split-bf16 MFMA GEMM (R13) -----------------------
template <int MFRAG>
__global__ __launch_bounds__(256) void k_mfma(
    const bf16_t* __restrict__ Ah, const bf16_t* __restrict__ Al,
    const bf16_t* __restrict__ Bh, const bf16_t* __restrict__ Bl,
    float* __restrict__ C, int M, int N, int K, int ntn)
{
    constexpr int MT   = MFRAG * 32;
    constexpr int AISS = MT / 64;

    __shared__ bf16_t sAh[MT * 32];
    __shared__ bf16_t sAl[MT * 32];
    __shared__ bf16_t sBh[128 * 32];
    __shared__ bf16_t sBl[128 * 32];

    const int nwg = gridDim.x;
    const int q   = nwg >> 3, r = nwg & 7;
    const int xcd = blockIdx.x & 7;
    const int idx = blockIdx.x >> 3;
    const int L   = (xcd < r ? xcd * (q + 1) : r * (q + 1) + (xcd - r) * q) + idx;
    const int rt  = L / ntn;
    const int ct  = L - rt * ntn;

    const int tid  = threadIdx.x;
    const int lane = tid & 63;
    const int wid  = tid >> 6;
    const int m0   = rt * MT;
    const int n0   = ct * 128;
    const int wm   = (wid >> 1) * (MFRAG * 16);
    const int wn   = (wid & 1) * 64;

    f32x4 acc[MFRAG][4] = {};

    int asrc[AISS], adst[AISS];
#pragma unroll
    for (int i = 0; i < AISS; ++i) {
        int p    = i * 256 + tid;
        int unit = p >> 3, sl = p & 7;
        int u    = sl ^ (unit & 7);
        int row  = (unit << 1) | (u >> 2);
        int kb   = u & 3;
        int gm   = m0 + row; if (gm >= M) gm = M - 1;
        asrc[i]  = gm * K + kb * 8;
        adst[i]  = p * 8;
    }
    int bsrc[2], bdst[2];
#pragma unroll
    for (int i = 0; i < 2; ++i) {
        int p    = i * 256 + tid;
        int unit = p >> 3, sl = p & 7;
        int u    = sl ^ (unit & 7);
        int row  = (unit << 1) | (u >> 2);
        int kb   = u & 3;
        bsrc[i]  = (n0 + row) * K + kb * 8;
        bdst[i]  = p * 8;
    }

    for (int k0 = 0; k0 < K; k0 += 32) {
#pragma unroll
        for (int i = 0; i < AISS; ++i) {
            __builtin_amdgcn_global_load_lds((gas_ptr)(Ah + asrc[i] + k0),
                                             (las_ptr)(sAh + adst[i]), 16, 0, 0);
            __builtin_amdgcn_global_load_lds((gas_ptr)(Al + asrc[i] + k0),
                                             (las_ptr)(sAl + adst[i]), 16, 0, 0);
        }
#pragma unroll
        for (int i = 0; i < 2; ++i) {
            __builtin_amdgcn_global_load_lds((gas_ptr)(Bh + bsrc[i] + k0),
                                             (las_ptr)(sBh + bdst[i]), 16, 0, 0);
            __builtin_amdgcn_global_load_lds((gas_ptr)(Bl + bsrc[i] + k0),
                                             (las_ptr)(sBl + bdst[i]), 16, 0, 0);
        }
        __syncthreads();

        const int kb = lane >> 4;
        bf16x8 a_h[MFRAG], a_l[MFRAG], b_h[4], b_l[4];
#pragma unroll
        for (int mf = 0; mf < MFRAG; ++mf) {
            int row  = wm + mf * 16 + (lane & 15);
            int unit = row >> 1;
            int sl   = (((row & 1) << 2) | kb) ^ (unit & 7);
            int off  = (unit * 8 + sl) * 8;
            a_h[mf] = *(const bf16x8*)(sAh + off);
            a_l[mf] = *(const bf16x8*)(sAl + off);
        }
#pragma unroll
        for (int nf = 0; nf < 4; ++nf) {
            int row  = wn + nf * 16 + (lane & 15);
            int unit = row >> 1;
            int sl   = (((row & 1) << 2) | kb) ^ (unit & 7);
            int off  = (unit * 8 + sl) * 8;
            b_h[nf] = *(const bf16x8*)(sBh + off);
            b_l[nf] = *(const bf16x8*)(sBl + off);
        }
#pragma unroll
        for (int mf = 0; mf < MFRAG; ++mf)
#pragma unroll
            for (int nf = 0; nf < 4; ++nf) {
                acc[mf][nf] = __builtin_amdgcn_mfma_f32_16x16x32_bf16(
                    a_h[mf], b_h[nf], acc[mf][nf], 0, 0, 0);
                acc[mf][nf] = __builtin_amdgcn_mfma_f32_16x16x32_bf16(
                    a_l[mf], b_h[nf], acc[mf][nf], 0, 0, 0);
                acc[mf][nf] = __builtin_amdgcn_mfma_f32_16x16x32_bf16(
                    a_h[mf], b_l[nf], acc[mf][nf], 0, 0, 0);
            }
        __syncthreads();
    }

    // C/D layout: col = lane&15, row = (lane>>4)*4 + reg  [learn_hip m89/m91]
    const int cn = lane & 15;
    const int cr = (lane >> 4) * 4;
#pragma unroll
    for (int mf = 0; mf < MFRAG; ++mf) {
#pragma unroll
        for (int r2 = 0; r2 < 4; ++r2) {
            const int m = m0 + wm + mf * 16 + cr + r2;
            if (m < M) {
                float* cp = C + (size_t)m * N + n0 + wn + cn;
                cp[0]  = acc[mf][0][r2];
                cp[16] = acc[mf][1][r2];
                cp[32] = acc[mf][2][r2];
                cp[48] = acc[mf][3][r2];
            }
        }
    }
}

// --- hidden gather: XCD-keyed slice, 2 rows/wave x 8 edges, LDS reduce -----
// All Lin/output offsets are int32 (41MB < 2^31) -> 32-bit voffset form.
__global__ __launch_bounds__(256) void k_agg_h(
    const float* __restrict__ Lin,
    bf16_t* __restrict__ OutH, bf16_t* __restrict__ OutL,
    const int* __restrict__ row_ptr, const int* __restrict__ cnt,
    const int2* __restrict__ ew, const float* __restrict__ dinv,
    const float* __restrict__ bias, int M)
{
    __shared__ float red[4][2][8][64];        // [wave][row][eg][col], 16 KB

    const int s    = blockIdx.x & 7;
    const int rg   = blockIdx.x >> 3;
    const int wid  = threadIdx.x >> 6;
    const int lane = threadIdx.x & 63;
    const int row0 = rg * 8 + wid * 2;
    if (row0 >= M) return;
    const int row1 = row0 + 1;
    const bool has1 = row1 < M;

    const int eg = lane >> 3;                 // edge sub-slot (0..7)
    const int cb = s * 64 + (lane & 7) * 4;   // first float4 col

    const int beg0 = row_ptr[row0];
    const int num0 = cnt[row0];
    const int beg1 = has1 ? row_ptr[row1] : beg0;
    const int num1 = has1 ? cnt[row1] : 0;

    float4 a0 = make_float4(0.f, 0.f, 0.f, 0.f);
    float4 a1 = make_float4(0.f, 0.f, 0.f, 0.f);
    float4 b0 = make_float4(0.f, 0.f, 0.f, 0.f);
    float4 b1 = make_float4(0.f, 0.f, 0.f, 0.f);

    const int nm = max(num0, num1);
    for (int e0 = 0; e0 < nm; e0 += 8) {
        const int  e  = e0 + eg;
        const bool p0 = e < num0;
        const bool p1 = e < num1;
        const int2 eA = ew[beg0 + (p0 ? e : 0)];
        const int2 eB = ew[beg1 + (p1 ? e : 0)];
        const int   oA = (p0 ? eA.x : 0) * 512 + cb;   // int32 offsets
        const int   oB = (p1 ? eB.x : 0) * 512 + cb;
        const float wA = p0 ? __int_as_float(eA.y) : 0.f;
        const float wB = p1 ? __int_as_float(eB.y) : 0.f;
        const float4 vA0 = *(const float4*)(Lin + oA);
        const float4 vA1 = *(const float4*)(Lin + oA + 32);
        const float4 vB0 = *(const float4*)(Lin + oB);
        const float4 vB1 = *(const float4*)(Lin + oB + 32);
        a0.x += wA * vA0.x; a0.y += wA * vA0.y; a0.z += wA * vA0.z; a0.w += wA * vA0.w;
        a1.x += wA * vA1.x; a1.y += wA * vA1.y; a1.z += wA * vA1.z; a1.w += wA * vA1.w;
        b0.x += wB * vB0.x; b0.y += wB * vB0.y; b0.z += wB * vB0.z; b0.w += wB * vB0.w;
        b1.x += wB * vB1.x; b1.y += wB * vB1.y; b1.z += wB * vB1.z; b1.w += wB * vB1.w;
    }

    // wave-local transpose-reduce (no cross-wave sync needed)
    float* r0 = &red[wid][0][eg][(lane & 7) * 4];
    *(float4*)r0        = a0;
    *(float4*)(r0 + 32) = a1;
    float* r1 = &red[wid][1][eg][(lane & 7) * 4];
    *(float4*)r1        = b0;
    *(float4*)(r1 + 32) = b1;
    float s0 = 0.f, s1 = 0.f;
#pragma unroll
    for (int g = 0; g < 8; ++g) {
        s0 += red[wid][0][g][lane];
        s1 += red[wid][1][g][lane];
    }

    // lane-parallel epilogue: lane owns column (s*64 + lane) for both rows
    const int col = s * 64 + lane;
    const float bc = bias[col];
    {
        const float dr = dinv[row0], dr2 = dr * dr;
        const int   eo = row0 * 512 + col;
        const float v  = Lin[eo];
        const float o  = fmaxf(s0 * dr + dr2 * v + bc, 0.f);
        const bf16_t h = (bf16_t)o;
        OutH[eo] = h;
        OutL[eo] = (bf16_t)(o - (float)h);
    }
    if (has1) {
        const float dr = dinv[row1], dr2 = dr * dr;
        const int   eo = row1 * 512 + col;
        const float v  = Lin[eo];
        const float o  = fmaxf(s1 * dr + dr2 * v + bc, 0.f);
        const bf16_t h = (bf16_t)o;
        OutH[eo] = h;
        OutL[eo] = (bf16_t)(o - (float)h);
    }
}

// ----- layer-4 gather: 4 slices, 8-edge x 8-col, LDS reduce, raw logits ----
__global__ __launch_bounds__(256) void k_agg_o(
    const float* __restrict__ Lin, float* __restrict__ OutF,
    const int* __restrict__ row_ptr, const int* __restrict__ cnt,
    const int2* __restrict__ ew, const float* __restrict__ dinv, int M)
{
    __shared__ float red[4][8][64];

    const int s   = blockIdx.x & 3;
    const int row = (blockIdx.x >> 2) * 4 + (threadIdx.x >> 6);
    if (row >= M) return;
    const int lane = threadIdx.x & 63;
    const int wid  = threadIdx.x >> 6;
    const int eg   = lane >> 3;
    const int cb   = s * 64 + (lane & 7) * 4;

    const int beg = row_ptr[row];
    const int num = cnt[row];

    float4 a0 = make_float4(0.f, 0.f, 0.f, 0.f);
    float4 a1 = make_float4(0.f, 0.f, 0.f, 0.f);

    int e0 = 0;
    for (; e0 + 16 <= num; e0 += 16) {
        const int2 eA = ew[beg + e0 + eg];
        const int2 eB = ew[beg + e0 + 8 + eg];
        const float wA = __int_as_float(eA.y);
        const float wB = __int_as_float(eB.y);
        const int oA = eA.x * 256 + cb;
        const int oB = eB.x * 256 + cb;
        const float4 vA0 = *(const float4*)(Lin + oA);
        const float4 vA1 = *(const float4*)(Lin + oA + 32);
        const float4 vB0 = *(const float4*)(Lin + oB);
        const float4 vB1 = *(const float4*)(Lin + oB + 32);
        a0.x += wA * vA0.x + wB * vB0.x;  a0.y += wA * vA0.y + wB * vB0.y;
        a0.z += wA * vA0.z + wB * vB0.z;  a0.w += wA * vA0.w + wB * vB0.w;
        a1.x += wA * vA1.x + wB * vB1.x;  a1.y += wA * vA1.y + wB * vB1.y;
        a1.z += wA * vA1.z + wB * vB1.z;  a1.w += wA * vA1.w + wB * vB1.w;
    }
    for (; e0 < num; e0 += 8) {
        const int e = e0 + eg;
        if (e < num) {
            const int2 ee = ew[beg + e];
            const float w = __int_as_float(ee.y);
            const int o = ee.x * 256 + cb;
            const float4 v0 = *(const float4*)(Lin + o);
            const float4 v1 = *(const float4*)(Lin + o + 32);
            a0.x += w * v0.x; a0.y += w * v0.y; a0.z += w * v0.z; a0.w += w * v0.w;
            a1.x += w * v1.x; a1.y += w * v1.y; a1.z += w * v1.z; a1.w += w * v1.w;
        }
    }

    float* rp = &red[wid][eg][(lane & 7) * 4];
    *(float4*)rp        = a0;
    *(float4*)(rp + 32) = a1;
    float sum = 0.f;
#pragma unroll
    for (int g = 0; g < 8; ++g) sum += red[wid][g][lane];

    const int col = s * 64 + lane;
    const float dr = dinv[row], dr2 = dr * dr;
    const int  eo = row * 256 + col;
    OutF[eo] = sum * dr + dr2 * Lin[eo];
}

// ---------------- in-place softmax over rows of 256 (+ bias) ---------------
__global__ __launch_bounds__(256) void k_softmax_bias(float* __restrict__ IO,
                                                      const float* __restrict__ bias, int M)
{
    int row  = blockIdx.x * 4 + (threadIdx.x >> 6);
    int lane = threadIdx.x & 63;
    if (row >= M) return;
    float* p = IO + row * 256 + lane * 4;
    float4 v = *(float4*)p;
    const float4 b = *(const float4*)(bias + lane * 4);
    v.x += b.x; v.y += b.y; v.z += b.z; v.w += b.w;
    float m = fmaxf(fmaxf(v.x, v.y), fmaxf(v.z, v.w));
#pragma unroll
    for (int off = 32; off > 0; off >>= 1) m = fmaxf(m, __shfl_xor(m, off));
    float e0 = expf(v.x - m), e1 = expf(v.y - m), e2 = expf(v.z - m), e3 = expf(v.w - m);
    float s = e0 + e1 + e2 + e3;
#pragma unroll
    for (int off = 32; off > 0; off >>= 1) s += __shfl_xor(s, off);
    float inv = 1.0f / s;
    v.x = e0 * inv; v.y = e1 * inv; v.z = e2 * inv; v.w = e3 * inv;
    *(float4*)p = v;
}

// ------------------------------- launcher ----------------------------------

extern "C" void kernel_launch(void* const* d_in, const int* in_sizes, int n_in,
                              void* d_out, int out_size, void* d_ws, size_t ws_size,
                              hipStream_t stream)
{
    const float* x    = (const float*)d_in[0];
    const int*   eidx = (const int*)d_in[1];      // int32 [2][E]
    const float* W1 = (const float*)d_in[2]; const float* b1 = (const float*)d_in[3];
    const float* W2 = (const float*)d_in[4]; const float* b2 = (const float*)d_in[5];
    const float* W3 = (const float*)d_in[6]; const float* b3 = (const float*)d_in[7];
    const float* W4 = (const float*)d_in[8]; const float* b4 = (const float*)d_in[9];

    const int M = in_sizes[0] / 512;     // 20000
    const int E = in_sizes[1] / 2;       // 320000
    const int DH = 512, DO = 256;

    const int* srcI = eidx;
    const int* dstI = eidx + E;

    // ---- workspace layout (bytes) ----
    char* ws = (char*)d_ws;
    int*    cnt     = (int*)   (ws + 0);                  // 80KB
    int*    row_ptr = (int*)   (ws + (1 << 17));
    int*    cursor  = (int*)   (ws + (2 << 17));
    float*  dinv    = (float*) (ws + (3 << 17));
    int2*   ew      = (int2*)  (ws + 655360);             // 2.56MB
    bf16_t* W1h = (bf16_t*)(ws + 4194304);
    bf16_t* W1l = (bf16_t*)(ws + 4718592);
    bf16_t* W2h = (bf16_t*)(ws + 5242880);
    bf16_t* W2l = (bf16_t*)(ws + 5767168);
    bf16_t* W3h = (bf16_t*)(ws + 6291456);
    bf16_t* W3l = (bf16_t*)(ws + 6815744);
    bf16_t* W4h = (bf16_t*)(ws + 7340032);
    bf16_t* W4l = (bf16_t*)(ws + 7602176);
    const size_t HALF = (size_t)20000 * 512 * 2;          // 20.48MB
    bf16_t* PH  = (bf16_t*)(ws + 7864320);                // activation pair (hi)
    bf16_t* PL  = (bf16_t*)(ws + 7864320 + HALF);         // activation pair (lo)
    float*  Lin = (float*) (ws + 7864320 + 2 * HALF);     // f32 GEMM out, 41MB
    float*  out = (float*)d_out;

    const int gE = (E + THREADS - 1) / THREADS;
    const int nRT   = (M + 127) / 128;                    // 157 row tiles (128)
    const int nRT64 = (M + 63) / 64;                      // 313 row tiles (64)
    const int gemmH = nRT * (DH / 128);                   // 628 (1D, remapped)
    const int gemmO = nRT64 * (DO / 128);                 // 626 -> 2.44 blk/CU
    const int gRows = (M + 3) / 4;                        // 5000
    const int gAggH = ((M + 7) / 8) * 8;                  // 2500 row-grps x 8 slices
    const int gAggO = gRows * 4;                          // 4 slices

    // ---- CSR build ----
    hipMemsetAsync(cnt, 0, (size_t)M * sizeof(int), stream);
    k_count<<<gE, THREADS, 0, stream>>>(dstI, cnt, E, M);
    k_scan <<<1, 1024, 0, stream>>>(cnt, row_ptr, cursor, dinv, M);
    k_fill <<<gE, THREADS, 0, stream>>>(srcI, dstI, dinv, cursor, ew, E, M);

    // ---- operand splits ----
    k_split<<<2048, THREADS, 0, stream>>>(x, PH, PL, M * DH / 4);
    {
        const int a = DH * DH / 4;            // 65536 (W1)
        const int b = a + DH * DH / 4;        // 131072 (W2)
        const int c = b + DH * DH / 4;        // 196608 (W3)
        const int d = c + DO * DH / 4;        // 229376 (W4)
        k_split_w<<<896, THREADS, 0, stream>>>(W1, W2, W3, W4,
                                               W1h, W2h, W3h, W4h,
                                               W1l, W2l, W3l, W4l, a, b, c, d);
    }

    // ---- Layer 1 ----
    k_mfma<4><<<gemmH, THREADS, 0, stream>>>(PH, PL, W1h, W1l, Lin, M, DH, 512, DH / 128);
    k_agg_h<<<gAggH, THREADS, 0, stream>>>(Lin, PH, PL, row_ptr, cnt, ew, dinv, b1, M);
    // ---- Layer 2 ----
    k_mfma<4><<<gemmH, THREADS, 0, stream>>>(PH, PL, W2h, W2l, Lin, M, DH, DH, DH / 128);
    k_agg_h<<<gAggH, THREADS, 0, stream>>>(Lin, PH, PL, row_ptr, cnt, ew, dinv, b2, M);
    // ---- Layer 3 ----
    k_mfma<4><<<gemmH, THREADS, 0, stream>>>(PH, PL, W3h, W3l, Lin, M, DH, DH, DH / 128);
    k_agg_h<<<gAggH, THREADS, 0, stream>>>(Lin, PH, PL, row_ptr, cnt, ew, dinv, b3, M);
    // ---- Layer 4: 64-row-tile GEMM, sliced gather, fused bias+softmax -----
    k_mfma<2><<<gemmO, THREADS, 0, stream>>>(PH, PL, W4h, W4l, Lin, M, DO, DH, DO / 128);
    k_agg_o<<<gAggO, THREADS, 0, stream>>>(Lin, out, row_ptr, cnt, ew, dinv, M);
    k_softmax_bias<<<gRows, THREADS, 0, stream>>>(out, b4, M);
}

// Round 17
// 432.970 us; speedup vs baseline: 1.0151x; 1.0151x over previous
//
#include <hip/hip_runtime.h>
#include <hip/hip_bf16.h>

// ---------------------------------------------------------------------------
// GCN forward, round 17 == byte-exact R15 (best measured: 433.2 us).
//   k_mfma<MFRAG>: R13 GEMM (128x128 hidden / 64x128 layer-4, BK=32,
//           unit-XOR swizzle on global source, XCD-bijective 1D remap).
//   k_agg_h: 2-rows-per-wave XCD-keyed sliced gather (16 loads in flight at
//           every degree), LDS transpose-reduce, lane-parallel epilogue.
//   k_agg_o: 4-slice gather + LDS reduce; k_softmax_bias final.
//   R16's int32-addressing + memset/fused-scan experiments were null ->
//   reverted to the proven configuration.
// ---------------------------------------------------------------------------

#define THREADS 256

typedef __bf16 bf16_t;
typedef __bf16 bf16x8 __attribute__((ext_vector_type(8)));
typedef __bf16 bf16x4 __attribute__((ext_vector_type(4)));
typedef float  f32x4  __attribute__((ext_vector_type(4)));

typedef const __attribute__((address_space(1))) void* gas_ptr;
typedef __attribute__((address_space(3))) void*       las_ptr;

// ------------------------------ CSR build ----------------------------------

__global__ void k_zero_int(int* __restrict__ p, int n) {
    int i = blockIdx.x * blockDim.x + threadIdx.x;
    if (i < n) p[i] = 0;
}

__global__ void k_count(const int* __restrict__ dst, int* __restrict__ cnt, int E, int n) {
    int i = blockIdx.x * blockDim.x + threadIdx.x;
    if (i < E) {
        int d = dst[i];
        if ((unsigned)d < (unsigned)n) atomicAdd(&cnt[d], 1);
    }
}

__global__ void k_dinv(const int* __restrict__ cnt, float* __restrict__ dinv, int n) {
    int i = blockIdx.x * blockDim.x + threadIdx.x;
    if (i < n) dinv[i] = rsqrtf((float)(cnt[i] + 1));   // +1 self-loop
}

__global__ __launch_bounds__(1024) void k_scan(const int* __restrict__ cnt,
                                               int* __restrict__ row_ptr,
                                               int* __restrict__ cursor, int n)
{
    __shared__ int sm[1024];
    const int t = threadIdx.x;
    const int chunk = (n + 1023) >> 10;
    const int lo = t * chunk, hi = min(n, lo + chunk);
    int s = 0;
    for (int i = lo; i < hi; ++i) s += cnt[i];
    sm[t] = s;
    __syncthreads();
    for (int off = 1; off < 1024; off <<= 1) {
        int v = (t >= off) ? sm[t - off] : 0;
        __syncthreads();
        sm[t] += v;
        __syncthreads();
    }
    int run = sm[t] - s;
    for (int i = lo; i < hi; ++i) {
        row_ptr[i] = run;
        cursor[i]  = run;
        run += cnt[i];
    }
}

__global__ void k_fill(const int* __restrict__ src, const int* __restrict__ dst,
                       const float* __restrict__ dinv, int* __restrict__ cursor,
                       int2* __restrict__ ew, int E, int n)
{
    int i = blockIdx.x * blockDim.x + threadIdx.x;
    if (i < E) {
        int s = src[i], d = dst[i];
        if ((unsigned)s >= (unsigned)n || (unsigned)d >= (unsigned)n) return;
        int pos = atomicAdd(&cursor[d], 1);
        ew[pos] = make_int2(s, __float_as_int(dinv[s]));
    }
}

// --------------------------- f32 -> hi/lo bf16 -----------------------------

__global__ void k_split(const float* __restrict__ in, bf16_t* __restrict__ hi,
                        bf16_t* __restrict__ lo, int n4)
{
    int i = blockIdx.x * blockDim.x + threadIdx.x;
    const int stride = gridDim.x * blockDim.x;
    for (; i < n4; i += stride) {
        float4 v = ((const float4*)in)[i];
        bf16x4 h, l;
        h[0] = (bf16_t)v.x; l[0] = (bf16_t)(v.x - (float)h[0]);
        h[1] = (bf16_t)v.y; l[1] = (bf16_t)(v.y - (float)h[1]);
        h[2] = (bf16_t)v.z; l[2] = (bf16_t)(v.z - (float)h[2]);
        h[3] = (bf16_t)v.w; l[3] = (bf16_t)(v.w - (float)h[3]);
        ((bf16x4*)hi)[i] = h;
        ((bf16x4*)lo)[i] = l;
    }
}

// fused 4-weight split
__global__ void k_split_w(const float* __restrict__ s0, const float* __restrict__ s1,
                          const float* __restrict__ s2, const float* __restrict__ s3,
                          bf16_t* __restrict__ h0, bf16_t* __restrict__ h1,
                          bf16_t* __restrict__ h2, bf16_t* __restrict__ h3,
                          bf16_t* __restrict__ l0, bf16_t* __restrict__ l1,
                          bf16_t* __restrict__ l2, bf16_t* __restrict__ l3,
                          int a, int b, int c, int d)
{
    int i = blockIdx.x * blockDim.x + threadIdx.x;
    const int stride = gridDim.x * blockDim.x;
    for (; i < d; i += stride) {
        const float* src; bf16_t* hh; bf16_t* ll; int j;
        if (i < a)      { src = s0; hh = h0; ll = l0; j = i; }
        else if (i < b) { src = s1; hh = h1; ll = l1; j = i - a; }
        else if (i < c) { src = s2; hh = h2; ll = l2; j = i - b; }
        else            { src = s3; hh = h3; ll = l3; j = i - c; }
        float4 v = ((const float4*)src)[j];
        bf16x4 h, l;
        h[0] = (bf16_t)v.x; l[0] = (bf16_t)(v.x - (float)h[0]);
        h[1] = (bf16_t)v.y; l[1] = (bf16_t)(v.y - (float)h[1]);
        h[2] = (bf16_t)v.z; l[2] = (bf16_t)(v.z - (float)h[2]);
        h[3] = (bf16_t)v.w; l[3] = (bf16_t)(v.w - (float)h[3]);
        ((bf16x4*)hh)[j] = h;
        ((bf16x4*)ll)[j] = l;
    }
}

// ------------------------ split-bf16 MFMA GEMM (R13) -----------------------
template <int MFRAG>
__global__ __launch_bounds__(256) void k_mfma(
    const bf16_t* __restrict__ Ah, const bf16_t* __restrict__ Al,
    const bf16_t* __restrict__ Bh, const bf16_t* __restrict__ Bl,
    float* __restrict__ C, int M, int N, int K, int ntn)
{
    constexpr int MT   = MFRAG * 32;
    constexpr int AISS = MT / 64;

    __shared__ bf16_t sAh[MT * 32];
    __shared__ bf16_t sAl[MT * 32];
    __shared__ bf16_t sBh[128 * 32];
    __shared__ bf16_t sBl[128 * 32];

    const int nwg = gridDim.x;
    const int q   = nwg >> 3, r = nwg & 7;
    const int xcd = blockIdx.x & 7;
    const int idx = blockIdx.x >> 3;
    const int L   = (xcd < r ? xcd * (q + 1) : r * (q + 1) + (xcd - r) * q) + idx;
    const int rt  = L / ntn;
    const int ct  = L - rt * ntn;

    const int tid  = threadIdx.x;
    const int lane = tid & 63;
    const int wid  = tid >> 6;
    const int m0   = rt * MT;
    const int n0   = ct * 128;
    const int wm   = (wid >> 1) * (MFRAG * 16);
    const int wn   = (wid & 1) * 64;

    f32x4 acc[MFRAG][4] = {};

    int asrc[AISS], adst[AISS];
#pragma unroll
    for (int i = 0; i < AISS; ++i) {
        int p    = i * 256 + tid;
        int unit = p >> 3, sl = p & 7;
        int u    = sl ^ (unit & 7);
        int row  = (unit << 1) | (u >> 2);
        int kb   = u & 3;
        int gm   = m0 + row; if (gm >= M) gm = M - 1;
        asrc[i]  = gm * K + kb * 8;
        adst[i]  = p * 8;
    }
    int bsrc[2], bdst[2];
#pragma unroll
    for (int i = 0; i < 2; ++i) {
        int p    = i * 256 + tid;
        int unit = p >> 3, sl = p & 7;
        int u    = sl ^ (unit & 7);
        int row  = (unit << 1) | (u >> 2);
        int kb   = u & 3;
        bsrc[i]  = (n0 + row) * K + kb * 8;
        bdst[i]  = p * 8;
    }

    for (int k0 = 0; k0 < K; k0 += 32) {
#pragma unroll
        for (int i = 0; i < AISS; ++i) {
            __builtin_amdgcn_global_load_lds((gas_ptr)(Ah + asrc[i] + k0),
                                             (las_ptr)(sAh + adst[i]), 16, 0, 0);
            __builtin_amdgcn_global_load_lds((gas_ptr)(Al + asrc[i] + k0),
                                             (las_ptr)(sAl + adst[i]), 16, 0, 0);
        }
#pragma unroll
        for (int i = 0; i < 2; ++i) {
            __builtin_amdgcn_global_load_lds((gas_ptr)(Bh + bsrc[i] + k0),
                                             (las_ptr)(sBh + bdst[i]), 16, 0, 0);
            __builtin_amdgcn_global_load_lds((gas_ptr)(Bl + bsrc[i] + k0),
                                             (las_ptr)(sBl + bdst[i]), 16, 0, 0);
        }
        __syncthreads();

        const int kb = lane >> 4;
        bf16x8 a_h[MFRAG], a_l[MFRAG], b_h[4], b_l[4];
#pragma unroll
        for (int mf = 0; mf < MFRAG; ++mf) {
            int row  = wm + mf * 16 + (lane & 15);
            int unit = row >> 1;
            int sl   = (((row & 1) << 2) | kb) ^ (unit & 7);
            int off  = (unit * 8 + sl) * 8;
            a_h[mf] = *(const bf16x8*)(sAh + off);
            a_l[mf] = *(const bf16x8*)(sAl + off);
        }
#pragma unroll
        for (int nf = 0; nf < 4; ++nf) {
            int row  = wn + nf * 16 + (lane & 15);
            int unit = row >> 1;
            int sl   = (((row & 1) << 2) | kb) ^ (unit & 7);
            int off  = (unit * 8 + sl) * 8;
            b_h[nf] = *(const bf16x8*)(sBh + off);
            b_l[nf] = *(const bf16x8*)(sBl + off);
        }
#pragma unroll
        for (int mf = 0; mf < MFRAG; ++mf)
#pragma unroll
            for (int nf = 0; nf < 4; ++nf) {
                acc[mf][nf] = __builtin_amdgcn_mfma_f32_16x16x32_bf16(
                    a_h[mf], b_h[nf], acc[mf][nf], 0, 0, 0);
                acc[mf][nf] = __builtin_amdgcn_mfma_f32_16x16x32_bf16(
                    a_l[mf], b_h[nf], acc[mf][nf], 0, 0, 0);
                acc[mf][nf] = __builtin_amdgcn_mfma_f32_16x16x32_bf16(
                    a_h[mf], b_l[nf], acc[mf][nf], 0, 0, 0);
            }
        __syncthreads();
    }

    // C/D layout: col = lane&15, row = (lane>>4)*4 + reg  [learn_hip m89/m91]
    const int cn = lane & 15;
    const int cr = (lane >> 4) * 4;
#pragma unroll
    for (int mf = 0; mf < MFRAG; ++mf) {
#pragma unroll
        for (int r2 = 0; r2 < 4; ++r2) {
            const int m = m0 + wm + mf * 16 + cr + r2;
            if (m < M) {
                float* cp = C + (size_t)m * N + n0 + wn + cn;
                cp[0]  = acc[mf][0][r2];
                cp[16] = acc[mf][1][r2];
                cp[32] = acc[mf][2][r2];
                cp[48] = acc[mf][3][r2];
            }
        }
    }
}

// --- hidden gather: XCD-keyed slice, 2 rows/wave x 8 edges, LDS reduce -----
__global__ __launch_bounds__(256) void k_agg_h(
    const float* __restrict__ Lin,
    bf16_t* __restrict__ OutH, bf16_t* __restrict__ OutL,
    const int* __restrict__ row_ptr, const int* __restrict__ cnt,
    const int2* __restrict__ ew, const float* __restrict__ dinv,
    const float* __restrict__ bias, int M)
{
    __shared__ float red[4][2][8][64];        // [wave][row][eg][col], 16 KB

    const int s    = blockIdx.x & 7;
    const int rg   = blockIdx.x >> 3;
    const int wid  = threadIdx.x >> 6;
    const int lane = threadIdx.x & 63;
    const int row0 = rg * 8 + wid * 2;
    if (row0 >= M) return;
    const int row1 = row0 + 1;
    const bool has1 = row1 < M;

    const int eg = lane >> 3;                 // edge sub-slot (0..7)
    const int cb = s * 64 + (lane & 7) * 4;   // first float4 col

    const int beg0 = row_ptr[row0];
    const int num0 = cnt[row0];
    const int beg1 = has1 ? row_ptr[row1] : beg0;
    const int num1 = has1 ? cnt[row1] : 0;

    float4 a0 = make_float4(0.f, 0.f, 0.f, 0.f);
    float4 a1 = make_float4(0.f, 0.f, 0.f, 0.f);
    float4 b0 = make_float4(0.f, 0.f, 0.f, 0.f);
    float4 b1 = make_float4(0.f, 0.f, 0.f, 0.f);

    const int nm = max(num0, num1);
    for (int e0 = 0; e0 < nm; e0 += 8) {
        const int  e  = e0 + eg;
        const bool p0 = e < num0;
        const bool p1 = e < num1;
        const int2 eA = ew[beg0 + (p0 ? e : 0)];
        const int2 eB = ew[beg1 + (p1 ? e : 0)];
        const int   sA = p0 ? eA.x : 0;       // clamp: never use poison index
        const int   sB = p1 ? eB.x : 0;
        const float wA = p0 ? __int_as_float(eA.y) : 0.f;
        const float wB = p1 ? __int_as_float(eB.y) : 0.f;
        const float* pA = Lin + (size_t)sA * 512 + cb;
        const float* pB = Lin + (size_t)sB * 512 + cb;
        const float4 vA0 = *(const float4*)pA;
        const float4 vA1 = *(const float4*)(pA + 32);
        const float4 vB0 = *(const float4*)pB;
        const float4 vB1 = *(const float4*)(pB + 32);
        a0.x += wA * vA0.x; a0.y += wA * vA0.y; a0.z += wA * vA0.z; a0.w += wA * vA0.w;
        a1.x += wA * vA1.x; a1.y += wA * vA1.y; a1.z += wA * vA1.z; a1.w += wA * vA1.w;
        b0.x += wB * vB0.x; b0.y += wB * vB0.y; b0.z += wB * vB0.z; b0.w += wB * vB0.w;
        b1.x += wB * vB1.x; b1.y += wB * vB1.y; b1.z += wB * vB1.z; b1.w += wB * vB1.w;
    }

    // wave-local transpose-reduce (no cross-wave sync needed)
    float* r0 = &red[wid][0][eg][(lane & 7) * 4];
    *(float4*)r0        = a0;
    *(float4*)(r0 + 32) = a1;
    float* r1 = &red[wid][1][eg][(lane & 7) * 4];
    *(float4*)r1        = b0;
    *(float4*)(r1 + 32) = b1;
    float s0 = 0.f, s1 = 0.f;
#pragma unroll
    for (int g = 0; g < 8; ++g) {
        s0 += red[wid][0][g][lane];
        s1 += red[wid][1][g][lane];
    }

    // lane-parallel epilogue: lane owns column (s*64 + lane) for both rows
    const int col = s * 64 + lane;
    const float bc = bias[col];
    {
        const float dr = dinv[row0], dr2 = dr * dr;
        const float v  = Lin[(size_t)row0 * 512 + col];
        const float o  = fmaxf(s0 * dr + dr2 * v + bc, 0.f);
        const bf16_t h = (bf16_t)o;
        const size_t eo = (size_t)row0 * 512 + col;
        OutH[eo] = h;
        OutL[eo] = (bf16_t)(o - (float)h);
    }
    if (has1) {
        const float dr = dinv[row1], dr2 = dr * dr;
        const float v  = Lin[(size_t)row1 * 512 + col];
        const float o  = fmaxf(s1 * dr + dr2 * v + bc, 0.f);
        const bf16_t h = (bf16_t)o;
        const size_t eo = (size_t)row1 * 512 + col;
        OutH[eo] = h;
        OutL[eo] = (bf16_t)(o - (float)h);
    }
}

// ----- layer-4 gather: 4 slices, 8-edge x 8-col, LDS reduce, raw logits ----
__global__ __launch_bounds__(256) void k_agg_o(
    const float* __restrict__ Lin, float* __restrict__ OutF,
    const int* __restrict__ row_ptr, const int* __restrict__ cnt,
    const int2* __restrict__ ew, const float* __restrict__ dinv, int M)
{
    __shared__ float red[4][8][64];

    const int s   = blockIdx.x & 3;
    const int row = (blockIdx.x >> 2) * 4 + (threadIdx.x >> 6);
    if (row >= M) return;
    const int lane = threadIdx.x & 63;
    const int wid  = threadIdx.x >> 6;
    const int eg   = lane >> 3;
    const int cb   = s * 64 + (lane & 7) * 4;

    const int beg = row_ptr[row];
    const int num = cnt[row];

    float4 a0 = make_float4(0.f, 0.f, 0.f, 0.f);
    float4 a1 = make_float4(0.f, 0.f, 0.f, 0.f);

    int e0 = 0;
    for (; e0 + 16 <= num; e0 += 16) {
        const int2 eA = ew[beg + e0 + eg];
        const int2 eB = ew[beg + e0 + 8 + eg];
        const float wA = __int_as_float(eA.y);
        const float wB = __int_as_float(eB.y);
        const float* pA = Lin + (size_t)eA.x * 256 + cb;
        const float* pB = Lin + (size_t)eB.x * 256 + cb;
        const float4 vA0 = *(const float4*)pA;
        const float4 vA1 = *(const float4*)(pA + 32);
        const float4 vB0 = *(const float4*)pB;
        const float4 vB1 = *(const float4*)(pB + 32);
        a0.x += wA * vA0.x + wB * vB0.x;  a0.y += wA * vA0.y + wB * vB0.y;
        a0.z += wA * vA0.z + wB * vB0.z;  a0.w += wA * vA0.w + wB * vB0.w;
        a1.x += wA * vA1.x + wB * vB1.x;  a1.y += wA * vA1.y + wB * vB1.y;
        a1.z += wA * vA1.z + wB * vB1.z;  a1.w += wA * vA1.w + wB * vB1.w;
    }
    for (; e0 < num; e0 += 8) {
        const int e = e0 + eg;
        if (e < num) {
            const int2 ee = ew[beg + e];
            const float w = __int_as_float(ee.y);
            const float* p = Lin + (size_t)ee.x * 256 + cb;
            const float4 v0 = *(const float4*)p;
            const float4 v1 = *(const float4*)(p + 32);
            a0.x += w * v0.x; a0.y += w * v0.y; a0.z += w * v0.z; a0.w += w * v0.w;
            a1.x += w * v1.x; a1.y += w * v1.y; a1.z += w * v1.z; a1.w += w * v1.w;
        }
    }

    float* rp = &red[wid][eg][(lane & 7) * 4];
    *(float4*)rp        = a0;
    *(float4*)(rp + 32) = a1;
    float sum = 0.f;
#pragma unroll
    for (int g = 0; g < 8; ++g) sum += red[wid][g][lane];

    const int col = s * 64 + lane;
    const float dr = dinv[row], dr2 = dr * dr;
    const float v  = Lin[(size_t)row * 256 + col];
    OutF[(size_t)row * 256 + col] = sum * dr + dr2 * v;
}

// ---------------- in-place softmax over rows of 256 (+ bias) ---------------
__global__ __launch_bounds__(256) void k_softmax_bias(float* __restrict__ IO,
                                                      const float* __restrict__ bias, int M)
{
    int row  = blockIdx.x * 4 + (threadIdx.x >> 6);
    int lane = threadIdx.x & 63;
    if (row >= M) return;
    float* p = IO + (size_t)row * 256 + lane * 4;
    float4 v = *(float4*)p;
    const float4 b = *(const float4*)(bias + lane * 4);
    v.x += b.x; v.y += b.y; v.z += b.z; v.w += b.w;
    float m = fmaxf(fmaxf(v.x, v.y), fmaxf(v.z, v.w));
#pragma unroll
    for (int off = 32; off > 0; off >>= 1) m = fmaxf(m, __shfl_xor(m, off));
    float e0 = expf(v.x - m), e1 = expf(v.y - m), e2 = expf(v.z - m), e3 = expf(v.w - m);
    float s = e0 + e1 + e2 + e3;
#pragma unroll
    for (int off = 32; off > 0; off >>= 1) s += __shfl_xor(s, off);
    float inv = 1.0f / s;
    v.x = e0 * inv; v.y = e1 * inv; v.z = e2 * inv; v.w = e3 * inv;
    *(float4*)p = v;
}

// ------------------------------- launcher ----------------------------------

extern "C" void kernel_launch(void* const* d_in, const int* in_sizes, int n_in,
                              void* d_out, int out_size, void* d_ws, size_t ws_size,
                              hipStream_t stream)
{
    const float* x    = (const float*)d_in[0];
    const int*   eidx = (const int*)d_in[1];      // int32 [2][E]
    const float* W1 = (const float*)d_in[2]; const float* b1 = (const float*)d_in[3];
    const float* W2 = (const float*)d_in[4]; const float* b2 = (const float*)d_in[5];
    const float* W3 = (const float*)d_in[6]; const float* b3 = (const float*)d_in[7];
    const float* W4 = (const float*)d_in[8]; const float* b4 = (const float*)d_in[9];

    const int M = in_sizes[0] / 512;     // 20000
    const int E = in_sizes[1] / 2;       // 320000
    const int DH = 512, DO = 256;

    const int* srcI = eidx;
    const int* dstI = eidx + E;

    // ---- workspace layout (bytes) ----
    char* ws = (char*)d_ws;
    int*    cnt     = (int*)   (ws + 0);                  // 80KB
    int*    row_ptr = (int*)   (ws + (1 << 17));
    int*    cursor  = (int*)   (ws + (2 << 17));
    float*  dinv    = (float*) (ws + (3 << 17));
    int2*   ew      = (int2*)  (ws + 655360);             // 2.56MB
    bf16_t* W1h = (bf16_t*)(ws + 4194304);
    bf16_t* W1l = (bf16_t*)(ws + 4718592);
    bf16_t* W2h = (bf16_t*)(ws + 5242880);
    bf16_t* W2l = (bf16_t*)(ws + 5767168);
    bf16_t* W3h = (bf16_t*)(ws + 6291456);
    bf16_t* W3l = (bf16_t*)(ws + 6815744);
    bf16_t* W4h = (bf16_t*)(ws + 7340032);
    bf16_t* W4l = (bf16_t*)(ws + 7602176);
    const size_t HALF = (size_t)20000 * 512 * 2;          // 20.48MB
    bf16_t* PH  = (bf16_t*)(ws + 7864320);                // activation pair (hi)
    bf16_t* PL  = (bf16_t*)(ws + 7864320 + HALF);         // activation pair (lo)
    float*  Lin = (float*) (ws + 7864320 + 2 * HALF);     // f32 GEMM out, 41MB
    float*  out = (float*)d_out;

    const int gN = (M + THREADS - 1) / THREADS;
    const int gE = (E + THREADS - 1) / THREADS;
    const int nRT   = (M + 127) / 128;                    // 157 row tiles (128)
    const int nRT64 = (M + 63) / 64;                      // 313 row tiles (64)
    const int gemmH = nRT * (DH / 128);                   // 628 (1D, remapped)
    const int gemmO = nRT64 * (DO / 128);                 // 626 -> 2.44 blk/CU
    const int gRows = (M + 3) / 4;                        // 5000
    const int gAggH = ((M + 7) / 8) * 8;                  // 2500 row-grps x 8 slices
    const int gAggO = gRows * 4;                          // 4 slices

    // ---- CSR build ----
    k_zero_int<<<gN, THREADS, 0, stream>>>(cnt, M);
    k_count   <<<gE, THREADS, 0, stream>>>(dstI, cnt, E, M);
    k_dinv    <<<gN, THREADS, 0, stream>>>(cnt, dinv, M);
    k_scan    <<<1, 1024, 0, stream>>>(cnt, row_ptr, cursor, M);
    k_fill    <<<gE, THREADS, 0, stream>>>(srcI, dstI, dinv, cursor, ew, E, M);

    // ---- operand splits ----
    k_split<<<2048, THREADS, 0, stream>>>(x, PH, PL, M * DH / 4);
    {
        const int a = DH * DH / 4;            // 65536 (W1)
        const int b = a + DH * DH / 4;        // 131072 (W2)
        const int c = b + DH * DH / 4;        // 196608 (W3)
        const int d = c + DO * DH / 4;        // 229376 (W4)
        k_split_w<<<896, THREADS, 0, stream>>>(W1, W2, W3, W4,
                                               W1h, W2h, W3h, W4h,
                                               W1l, W2l, W3l, W4l, a, b, c, d);
    }

    // ---- Layer 1 ----
    k_mfma<4><<<gemmH, THREADS, 0, stream>>>(PH, PL, W1h, W1l, Lin, M, DH, 512, DH / 128);
    k_agg_h<<<gAggH, THREADS, 0, stream>>>(Lin, PH, PL, row_ptr, cnt, ew, dinv, b1, M);
    // ---- Layer 2 ----
    k_mfma<4><<<gemmH, THREADS, 0, stream>>>(PH, PL, W2h, W2l, Lin, M, DH, DH, DH / 128);
    k_agg_h<<<gAggH, THREADS, 0, stream>>>(Lin, PH, PL, row_ptr, cnt, ew, dinv, b2, M);
    // ---- Layer 3 ----
    k_mfma<4><<<gemmH, THREADS, 0, stream>>>(PH, PL, W3h, W3l, Lin, M, DH, DH, DH / 128);
    k_agg_h<<<gAggH, THREADS, 0, stream>>>(Lin, PH, PL, row_ptr, cnt, ew, dinv, b3, M);
    // ---- Layer 4: 64-row-tile GEMM, sliced gather, fused bias+softmax -----
    k_mfma<2><<<gemmO, THREADS, 0, stream>>>(PH, PL, W4h, W4l, Lin, M, DO, DH, DO / 128);
    k_agg_o<<<gAggO, THREADS, 0, stream>>>(Lin, out, row_ptr, cnt, ew, dinv, M);
    k_softmax_bias<<<gRows, THREADS, 0, stream>>>(out, b4, M);
}